// Round 1
// baseline (6649.543 us; speedup 1.0000x reference)
//
#include <hip/hip_runtime.h>
#include <hip/hip_bf16.h>
#include <math.h>

// ---------------- problem constants ----------------
#define BATCH   4096
#define CH      64          // latent channels
#define KCB     512         // codebook size
#define PTOT    (BATCH*49)  // 200704 spatial positions

// d_out layout (floats): x_tilde [4096,1,28,28], z_e_x [4096,64,7,7], z_q_x [4096,64,7,7]
#define XT_N    (BATCH*784)
#define ZE_OFF  (XT_N)
#define ZQ_OFF  (XT_N + BATCH*3136)

// workspace layout (bytes)
#define WS_C1   0                       // conv1 raw: 4096*32*196 floats = 102,760,448 B
#define WS_C2   102760448ULL            // conv2 raw: 4096*16*784 floats = 205,520,896 B
#define WS_ST   308281344ULL            // stats: double sum1[32] sq1[32] sum2[16] sq2[16]
#define WS_BN   308282112ULL            // bn params: float s1[32] h1[32] s2[16] h2[16]

#define FMA4(acc, xx, ww) \
    acc = fmaf((xx).x, (ww).x, acc); acc = fmaf((xx).y, (ww).y, acc); \
    acc = fmaf((xx).z, (ww).z, acc); acc = fmaf((xx).w, (ww).w, acc);

// ---------------- K0: zero the stats accumulators ----------------
__global__ void k_zero(double* __restrict__ stats) {
    int t = threadIdx.x;
    if (t < 96) stats[t] = 0.0;
}

// ---------------- K1: gather + VQ argmin + z_e_x/z_q_x ----------------
// grid 784 x 256 threads; one position (b,hw) per thread
__global__ __launch_bounds__(256) void k1_encode(
    const int* __restrict__ xidx, const float* __restrict__ encW,
    const float* __restrict__ emb, float* __restrict__ out)
{
    __shared__ float emb_s[KCB * CH];   // 128 KiB
    __shared__ float ee_s[KCB];

    const int tid = threadIdx.x;

    // stage codebook (linear float4 copy)
    {
        const float4* eg = (const float4*)emb;
        float4* es = (float4*)emb_s;
        #pragma unroll
        for (int j = 0; j < 32; ++j) es[tid + j*256] = eg[tid + j*256];
    }
    __syncthreads();
    for (int k = tid; k < KCB; k += 256) {
        float s = 0.f;
        #pragma unroll
        for (int c = 0; c < CH; ++c) { float e = emb_s[k*CH + c]; s = fmaf(e, e, s); }
        ee_s[k] = s;
    }
    __syncthreads();

    const int p  = blockIdx.x*256 + tid;     // < 200704 exactly
    const int b  = p / 49;
    const int hw = p - b*49;
    const long long row = xidx[b];
    const float* rp = encW + row*3136LL + hw;
    float* zep = out + ZE_OFF + (long long)b*3136 + hw;

    float z[CH];
    float zz = 0.f;
    #pragma unroll
    for (int c = 0; c < CH; ++c) {
        float v = rp[c*49];
        z[c] = v;
        zep[c*49] = v;                       // z_e_x is an exact row copy
        zz = fmaf(v, v, zz);
    }

    float d0 = 3.4e38f, d1 = 3.4e38f;
    int k0 = 0, k1i = 1;
    for (int k = 0; k < KCB; k += 2) {
        const float4* e4 = (const float4*)(emb_s + (k << 6));
        float a0=0.f,a1=0.f,a2=0.f,a3=0.f, c0=0.f,c1=0.f,c2=0.f,c3=0.f;
        #pragma unroll
        for (int j = 0; j < 16; ++j) {
            float4 ea = e4[j];
            float4 eb = e4[j + 16];
            a0 = fmaf(z[4*j+0], ea.x, a0);
            a1 = fmaf(z[4*j+1], ea.y, a1);
            a2 = fmaf(z[4*j+2], ea.z, a2);
            a3 = fmaf(z[4*j+3], ea.w, a3);
            c0 = fmaf(z[4*j+0], eb.x, c0);
            c1 = fmaf(z[4*j+1], eb.y, c1);
            c2 = fmaf(z[4*j+2], eb.z, c2);
            c3 = fmaf(z[4*j+3], eb.w, c3);
        }
        float dotA = (a0+a1) + (a2+a3);
        float dotB = (c0+c1) + (c2+c3);
        float dA = (zz - 2.f*dotA) + ee_s[k];
        float dB = (zz - 2.f*dotB) + ee_s[k+1];
        if (dA < d0)      { d1 = d0; k1i = k0; d0 = dA; k0 = k; }
        else if (dA < d1) { d1 = dA; k1i = k; }
        if (dB < d0)      { d1 = d0; k1i = k0; d0 = dB; k0 = k+1; }
        else if (dB < d1) { d1 = dB; k1i = k+1; }
    }

    // fp64 refine of near-ties -> effectively exact argmin
    if (d1 - d0 < fmaxf(1e-6f, 1e-3f * fabsf(d0))) {
        double D0 = 0.0, D1 = 0.0;
        #pragma unroll
        for (int c = 0; c < CH; ++c) {
            double f0 = (double)z[c] - (double)emb_s[k0*CH + c];
            double f1 = (double)z[c] - (double)emb_s[k1i*CH + c];
            D0 += f0*f0; D1 += f1*f1;
        }
        if (D1 < D0 || (D1 == D0 && k1i < k0)) k0 = k1i;
    }

    float* zqp = out + ZQ_OFF + (long long)b*3136 + hw;
    #pragma unroll
    for (int c = 0; c < CH; ++c) zqp[c*49] = emb_s[k0*CH + c];
}

// ---------------- K2: deconv1 (64->32, 7->14) + bias, BN1 stats ----------------
// grid 4096 (one image) x 256
__global__ __launch_bounds__(256) void k2_deconv1(
    const float* __restrict__ zq, const float* __restrict__ w1,
    const float* __restrict__ b1, float* __restrict__ c1raw,
    double* __restrict__ stats)
{
    __shared__ float w_s[32768];        // [oc=32][khw=16][ic=64] 128 KiB
    __shared__ float x_s[81 * 64];      // padded [9][9][64] 20.25 KiB
    __shared__ float bs[32], bq[32];

    const int tid = threadIdx.x;
    const int b = blockIdx.x;

    for (int i = tid; i < 32768; i += 256) {
        int ic = i >> 9;                // w1 is [ic][oc][kh][kw]
        int r  = i & 511;               // oc*16 + khw
        w_s[(r << 6) + ic] = w1[i];
    }
    for (int i = tid; i < 81*64; i += 256) x_s[i] = 0.f;
    if (tid < 32) { bs[tid] = 0.f; bq[tid] = 0.f; }
    __syncthreads();

    const float* zb = zq + (long long)b*3136;
    for (int i = tid; i < 3136; i += 256) {
        int c = i / 49, hw = i - c*49;
        int ih = hw / 7, iw = hw - ih*7;
        x_s[((ih+1)*9 + (iw+1))*64 + c] = zb[i];
    }
    __syncthreads();

    const int m   = tid & 7;
    const int oc0 = m << 2;
    const float bias0 = b1[oc0], bias1v = b1[oc0+1], bias2v = b1[oc0+2], bias3v = b1[oc0+3];
    float s0=0.f,s1=0.f,s2=0.f,s3=0.f, q0=0.f,q1=0.f,q2=0.f,q3=0.f;
    float* c1b = c1raw + (long long)b*6272;

    for (int pass = 0; pass < 7; ++pass) {
        int px = (tid >> 3) + (pass << 5);
        if (px >= 196) break;
        int oh = px / 14, ow = px - oh*14;
        int ihb = (oh+1) >> 1, ph = (oh+1) & 1;
        int iwb = (ow+1) >> 1, pw = (ow+1) & 1;
        float a0=0.f,a1=0.f,a2=0.f,a3=0.f;
        #pragma unroll
        for (int dh = 0; dh < 2; ++dh) {
            int ih = ihb - dh;
            int kh = ph + (dh << 1);
            #pragma unroll
            for (int dw = 0; dw < 2; ++dw) {
                int iw = iwb - dw;
                int kw = pw + (dw << 1);
                const float4* xv = (const float4*)&x_s[(((ih+1)*9 + (iw+1)) << 6)];
                const float4* wv = (const float4*)&w_s[(((oc0 << 4) + (kh << 2) + kw) << 6)];
                #pragma unroll
                for (int c4 = 0; c4 < 16; ++c4) {
                    float4 xx = xv[c4];
                    float4 wa = wv[c4];
                    float4 wb = wv[c4 + 256];
                    float4 wc = wv[c4 + 512];
                    float4 wd = wv[c4 + 768];
                    FMA4(a0, xx, wa); FMA4(a1, xx, wb); FMA4(a2, xx, wc); FMA4(a3, xx, wd);
                }
            }
        }
        float v0 = a0 + bias0, v1 = a1 + bias1v, v2 = a2 + bias2v, v3 = a3 + bias3v;
        c1b[(oc0+0)*196 + px] = v0;
        c1b[(oc0+1)*196 + px] = v1;
        c1b[(oc0+2)*196 + px] = v2;
        c1b[(oc0+3)*196 + px] = v3;
        s0 += v0; q0 = fmaf(v0, v0, q0);
        s1 += v1; q1 = fmaf(v1, v1, q1);
        s2 += v2; q2 = fmaf(v2, v2, q2);
        s3 += v3; q3 = fmaf(v3, v3, q3);
    }

    atomicAdd(&bs[oc0+0], s0); atomicAdd(&bq[oc0+0], q0);
    atomicAdd(&bs[oc0+1], s1); atomicAdd(&bq[oc0+1], q1);
    atomicAdd(&bs[oc0+2], s2); atomicAdd(&bq[oc0+2], q2);
    atomicAdd(&bs[oc0+3], s3); atomicAdd(&bq[oc0+3], q3);
    __syncthreads();
    if (tid < 32) {
        atomicAdd(&stats[tid],      (double)bs[tid]);
        atomicAdd(&stats[32 + tid], (double)bq[tid]);
    }
}

// ---------------- K3/K5: fold BN stats into scale/shift ----------------
__global__ void k_bnfin(const double* __restrict__ stats, const float* __restrict__ g,
                        const float* __restrict__ be, float* __restrict__ bn,
                        int soff, int boff, int nch, double n)
{
    int t = threadIdx.x;
    if (t < nch) {
        double mean = stats[soff + t] / n;
        double var  = stats[soff + nch + t] / n - mean*mean;
        double rstd = 1.0 / sqrt(var + 1e-5);
        double sc   = (double)g[t] * rstd;
        bn[boff + t]       = (float)sc;
        bn[boff + nch + t] = (float)((double)be[t] - mean*sc);
    }
}

// ---------------- K4: BN1+ReLU on read, deconv2 (32->16, 14->28), BN2 stats ----------------
__global__ __launch_bounds__(256) void k4_deconv2(
    const float* __restrict__ c1raw, const float* __restrict__ w2,
    const float* __restrict__ b2, const float* __restrict__ bn,
    float* __restrict__ c2raw, double* __restrict__ stats)
{
    __shared__ float w_s[8192];         // [oc=16][khw=16][ic=32] 32 KiB
    __shared__ float x_s[16*16*32];     // padded [16][16][32] 32 KiB
    __shared__ float bs[16], bq[16];

    const int tid = threadIdx.x;
    const int b = blockIdx.x;

    for (int i = tid; i < 8192; i += 256) {
        int ic = i >> 8;                // w2 is [ic=32][oc=16][kh][kw]
        int r  = i & 255;               // oc*16 + khw
        w_s[(r << 5) + ic] = w2[i];
    }
    for (int i = tid; i < 16*16*32; i += 256) x_s[i] = 0.f;
    if (tid < 16) { bs[tid] = 0.f; bq[tid] = 0.f; }
    __syncthreads();

    const float* cb = c1raw + (long long)b*6272;
    for (int i = tid; i < 6272; i += 256) {
        int ic = i / 196, hw = i - ic*196;
        int ih = hw / 14, iw = hw - ih*14;
        float v = fmaxf(fmaf(cb[i], bn[ic], bn[32 + ic]), 0.f);
        x_s[((ih+1)*16 + (iw+1))*32 + ic] = v;
    }
    __syncthreads();

    const int m   = tid & 3;
    const int oc0 = m << 2;
    const float bias0 = b2[oc0], bias1v = b2[oc0+1], bias2v = b2[oc0+2], bias3v = b2[oc0+3];
    float s0=0.f,s1=0.f,s2=0.f,s3=0.f, q0=0.f,q1=0.f,q2=0.f,q3=0.f;
    float* c2b = c2raw + (long long)b*12544;

    for (int pass = 0; pass < 13; ++pass) {
        int px = (tid >> 2) + (pass << 6);
        if (px >= 784) break;
        int oh = px / 28, ow = px - oh*28;
        int ihb = (oh+1) >> 1, ph = (oh+1) & 1;
        int iwb = (ow+1) >> 1, pw = (ow+1) & 1;
        float a0=0.f,a1=0.f,a2=0.f,a3=0.f;
        #pragma unroll
        for (int dh = 0; dh < 2; ++dh) {
            int ih = ihb - dh;
            int kh = ph + (dh << 1);
            #pragma unroll
            for (int dw = 0; dw < 2; ++dw) {
                int iw = iwb - dw;
                int kw = pw + (dw << 1);
                const float4* xv = (const float4*)&x_s[(((ih+1)*16 + (iw+1)) << 5)];
                const float4* wv = (const float4*)&w_s[(((oc0 << 4) + (kh << 2) + kw) << 5)];
                #pragma unroll
                for (int c4 = 0; c4 < 8; ++c4) {
                    float4 xx = xv[c4];
                    float4 wa = wv[c4];
                    float4 wb = wv[c4 + 128];
                    float4 wc = wv[c4 + 256];
                    float4 wd = wv[c4 + 384];
                    FMA4(a0, xx, wa); FMA4(a1, xx, wb); FMA4(a2, xx, wc); FMA4(a3, xx, wd);
                }
            }
        }
        float v0 = a0 + bias0, v1 = a1 + bias1v, v2 = a2 + bias2v, v3 = a3 + bias3v;
        c2b[(oc0+0)*784 + px] = v0;
        c2b[(oc0+1)*784 + px] = v1;
        c2b[(oc0+2)*784 + px] = v2;
        c2b[(oc0+3)*784 + px] = v3;
        s0 += v0; q0 = fmaf(v0, v0, q0);
        s1 += v1; q1 = fmaf(v1, v1, q1);
        s2 += v2; q2 = fmaf(v2, v2, q2);
        s3 += v3; q3 = fmaf(v3, v3, q3);
    }

    atomicAdd(&bs[oc0+0], s0); atomicAdd(&bq[oc0+0], q0);
    atomicAdd(&bs[oc0+1], s1); atomicAdd(&bq[oc0+1], q1);
    atomicAdd(&bs[oc0+2], s2); atomicAdd(&bq[oc0+2], q2);
    atomicAdd(&bs[oc0+3], s3); atomicAdd(&bq[oc0+3], q3);
    __syncthreads();
    if (tid < 16) {
        atomicAdd(&stats[64 + tid], (double)bs[tid]);
        atomicAdd(&stats[80 + tid], (double)bq[tid]);
    }
}

// ---------------- K6: BN2+ReLU on read, 3x3 conv 16->1, sigmoid ----------------
__global__ __launch_bounds__(256) void k6_conv(
    const float* __restrict__ c2raw, const float* __restrict__ cw,
    const float* __restrict__ cbias, const float* __restrict__ bn,
    float* __restrict__ out)
{
    __shared__ float x_s[30*30*16];     // padded [30][30][16] 56.25 KiB
    __shared__ float w_s[144];          // [khw=9][ic=16]

    const int tid = threadIdx.x;
    const int b = blockIdx.x;

    for (int i = tid; i < 30*30*16; i += 256) x_s[i] = 0.f;
    if (tid < 144) {
        int ic = tid / 9, khw = tid - ic*9;   // cw is [ic=16][kh][kw]
        w_s[khw*16 + ic] = cw[tid];
    }
    __syncthreads();

    const float* cr = c2raw + (long long)b*12544;
    for (int i = tid; i < 12544; i += 256) {
        int c = i / 784, hw = i - c*784;
        int ih = hw / 28, iw = hw - ih*28;
        float v = fmaxf(fmaf(cr[i], bn[64 + c], bn[80 + c]), 0.f);
        x_s[((ih+1)*30 + (iw+1))*16 + c] = v;
    }
    __syncthreads();

    const float bias = cbias[0];
    for (int pass = 0; pass < 4; ++pass) {
        int px = tid + (pass << 8);
        if (px >= 784) break;
        int oh = px / 28, ow = px - oh*28;
        float a0=0.f,a1=0.f,a2=0.f,a3=0.f;
        #pragma unroll
        for (int kh = 0; kh < 3; ++kh) {
            #pragma unroll
            for (int kw = 0; kw < 3; ++kw) {
                const float4* xv = (const float4*)&x_s[(((oh+kh)*30 + (ow+kw)) << 4)];
                const float4* wv = (const float4*)&w_s[((kh*3 + kw) << 4)];
                #pragma unroll
                for (int c4 = 0; c4 < 4; ++c4) {
                    float4 xx = xv[c4];
                    float4 ww = wv[c4];
                    a0 = fmaf(xx.x, ww.x, a0);
                    a1 = fmaf(xx.y, ww.y, a1);
                    a2 = fmaf(xx.z, ww.z, a2);
                    a3 = fmaf(xx.w, ww.w, a3);
                }
            }
        }
        float t = ((a0+a1) + (a2+a3)) + bias;
        out[(long long)b*784 + px] = 1.f / (1.f + expf(-t));
    }
}

// ---------------- launch ----------------
extern "C" void kernel_launch(void* const* d_in, const int* in_sizes, int n_in,
                              void* d_out, int out_size, void* d_ws, size_t ws_size,
                              hipStream_t stream) {
    const int*   x    = (const int*)d_in[0];
    const float* encW = (const float*)d_in[1];
    const float* emb  = (const float*)d_in[2];
    const float* w1   = (const float*)d_in[3];
    const float* b1   = (const float*)d_in[4];
    const float* g1   = (const float*)d_in[5];
    const float* be1  = (const float*)d_in[6];
    const float* w2   = (const float*)d_in[7];
    const float* b2   = (const float*)d_in[8];
    const float* g2   = (const float*)d_in[9];
    const float* be2  = (const float*)d_in[10];
    const float* cw   = (const float*)d_in[11];
    const float* cb   = (const float*)d_in[12];
    float* out = (float*)d_out;

    char* ws = (char*)d_ws;
    float*  c1raw = (float*)(ws + WS_C1);
    float*  c2raw = (float*)(ws + WS_C2);
    double* stats = (double*)(ws + WS_ST);
    float*  bn    = (float*)(ws + WS_BN);

    k_zero<<<1, 128, 0, stream>>>(stats);
    k1_encode<<<784, 256, 0, stream>>>(x, encW, emb, out);
    k2_deconv1<<<4096, 256, 0, stream>>>(out + ZQ_OFF, w1, b1, c1raw, stats);
    k_bnfin<<<1, 64, 0, stream>>>(stats, g1, be1, bn, 0, 0, 32, 4096.0*196.0);
    k4_deconv2<<<4096, 256, 0, stream>>>(c1raw, w2, b2, bn, c2raw, stats);
    k_bnfin<<<1, 64, 0, stream>>>(stats, g2, be2, bn, 64, 64, 16, 4096.0*784.0);
    k6_conv<<<4096, 256, 0, stream>>>(c2raw, cw, cb, bn, out);
}

// Round 2
// 2171.593 us; speedup vs baseline: 3.0621x; 3.0621x over previous
//
#include <hip/hip_runtime.h>
#include <hip/hip_bf16.h>
#include <math.h>

// ---------------- problem constants ----------------
#define BATCH   4096
#define CH      64          // latent channels
#define KCB     512         // codebook size

// d_out layout (floats): x_tilde [4096,1,28,28], z_e_x [4096,64,7,7], z_q_x [4096,64,7,7]
#define XT_N    (BATCH*784)
#define ZE_OFF  (XT_N)
#define ZQ_OFF  (XT_N + BATCH*3136)

// workspace layout (bytes)
#define WS_C1   0                       // conv1 raw: 4096*32*196 floats = 102,760,448 B
#define WS_C2   102760448ULL            // conv2 raw: 4096*16*784 floats = 205,520,896 B
#define WS_ST   308281344ULL            // stats: double sum1[32] sq1[32] sum2[16] sq2[16]
#define WS_BN   308282112ULL            // bn params: float s1[32] h1[32] s2[16] h2[16]
#define WS_W2T  308282496ULL            // w2 transposed [16 taps][32 ic][16 oc] = 32 KiB
// w1t lives in the head of the C2 region: written by prep, read by k2, clobbered by k4 (safe: stream order)
#define WS_W1T  WS_C2

// ---------------- K0: zero the stats accumulators ----------------
__global__ void k_zero(double* __restrict__ stats) {
    int t = threadIdx.x;
    if (t < 96) stats[t] = 0.0;
}

// ---------------- prep: transpose weights for scalar-load access ----------------
// w1 [ic64][oc32][kh][kw] -> w1t [(kh*4+kw)*64+ic][oc32]
// w2 [ic32][oc16][kh][kw] -> w2t [(kh*4+kw)*32+ic][oc16]
__global__ void k_prep(const float* __restrict__ w1, const float* __restrict__ w2,
                       float* __restrict__ w1t, float* __restrict__ w2t) {
    int t = threadIdx.x + blockIdx.x * 256;
    if (t < 32768) {
        int ic = t >> 9, oc = (t >> 4) & 31, khw = t & 15;
        w1t[(khw * 64 + ic) * 32 + oc] = w1[t];
    }
    if (t < 8192) {
        int ic = t >> 8, oc = (t >> 4) & 15, khw = t & 15;
        w2t[(khw * 32 + ic) * 16 + oc] = w2[t];
    }
}

// ---------------- K1: gather + VQ argmin + z_e_x/z_q_x ----------------
// codebook read via wave-uniform global pointers -> s_load broadcast (no LDS stage)
__global__ __launch_bounds__(256) void k1_encode(
    const int* __restrict__ xidx, const float* __restrict__ encW,
    const float* __restrict__ emb, float* __restrict__ out)
{
    __shared__ float ee_s[KCB];
    const int tid = threadIdx.x;

    for (int k = tid; k < KCB; k += 256) {
        const float* e = emb + (k << 6);
        float s = 0.f;
        #pragma unroll
        for (int c = 0; c < CH; ++c) s = fmaf(e[c], e[c], s);
        ee_s[k] = s;
    }
    __syncthreads();

    const int p  = blockIdx.x*256 + tid;     // < 200704 exactly
    const int b  = p / 49;
    const int hw = p - b*49;
    const long long row = xidx[b];
    const float* rp = encW + row*3136LL + hw;
    float* zep = out + ZE_OFF + (long long)b*3136 + hw;

    float z[CH];
    float zz = 0.f;
    #pragma unroll
    for (int c = 0; c < CH; ++c) {
        float v = rp[c*49];
        z[c] = v;
        zep[c*49] = v;                       // z_e_x is an exact row copy
        zz = fmaf(v, v, zz);
    }

    float d0 = 3.4e38f, d1 = 3.4e38f;
    int k0 = 0, k1i = 1;
    for (int k = 0; k < KCB; k += 2) {
        const float4* ea4 = (const float4*)(emb + (k << 6));      // uniform -> s_load
        const float4* eb4 = (const float4*)(emb + (k << 6) + 64); // uniform -> s_load
        float a0=0.f,a1=0.f,a2=0.f,a3=0.f, c0=0.f,c1=0.f,c2=0.f,c3=0.f;
        #pragma unroll
        for (int j = 0; j < 16; ++j) {
            float4 ea = ea4[j];
            float4 eb = eb4[j];
            a0 = fmaf(z[4*j+0], ea.x, a0);
            a1 = fmaf(z[4*j+1], ea.y, a1);
            a2 = fmaf(z[4*j+2], ea.z, a2);
            a3 = fmaf(z[4*j+3], ea.w, a3);
            c0 = fmaf(z[4*j+0], eb.x, c0);
            c1 = fmaf(z[4*j+1], eb.y, c1);
            c2 = fmaf(z[4*j+2], eb.z, c2);
            c3 = fmaf(z[4*j+3], eb.w, c3);
        }
        float dotA = (a0+a1) + (a2+a3);
        float dotB = (c0+c1) + (c2+c3);
        float dA = (zz - 2.f*dotA) + ee_s[k];
        float dB = (zz - 2.f*dotB) + ee_s[k+1];
        if (dA < d0)      { d1 = d0; k1i = k0; d0 = dA; k0 = k; }
        else if (dA < d1) { d1 = dA; k1i = k; }
        if (dB < d0)      { d1 = d0; k1i = k0; d0 = dB; k0 = k+1; }
        else if (dB < d1) { d1 = dB; k1i = k+1; }
    }

    // fp64 refine of near-ties -> effectively exact argmin
    if (d1 - d0 < fmaxf(1e-6f, 1e-3f * fabsf(d0))) {
        double D0 = 0.0, D1 = 0.0;
        #pragma unroll
        for (int c = 0; c < CH; ++c) {
            double f0 = (double)z[c] - (double)emb[k0*CH + c];
            double f1 = (double)z[c] - (double)emb[k1i*CH + c];
            D0 += f0*f0; D1 += f1*f1;
        }
        if (D1 < D0 || (D1 == D0 && k1i < k0)) k0 = k1i;
    }

    float* zqp = out + ZQ_OFF + (long long)b*3136 + hw;
    const float* e0 = emb + k0*CH;
    #pragma unroll
    for (int c = 0; c < CH; ++c) zqp[c*49] = e0[c];
}

#define OC8(xc, wr) { \
    acc[0]=fmaf((xc),(wr)[0],acc[0]); acc[1]=fmaf((xc),(wr)[1],acc[1]); \
    acc[2]=fmaf((xc),(wr)[2],acc[2]); acc[3]=fmaf((xc),(wr)[3],acc[3]); \
    acc[4]=fmaf((xc),(wr)[4],acc[4]); acc[5]=fmaf((xc),(wr)[5],acc[5]); \
    acc[6]=fmaf((xc),(wr)[6],acc[6]); acc[7]=fmaf((xc),(wr)[7],acc[7]); }

// ---------------- K2: deconv1 (64->32, 7->14) + bias, BN1 stats ----------------
// 2 images per block; wave w -> 8 oc; lanes -> parity-class pixels; weights via s_load
__global__ __launch_bounds__(256) void k2_deconv1(
    const float* __restrict__ zq, const float* __restrict__ w1t,
    const float* __restrict__ b1, float* __restrict__ c1raw,
    double* __restrict__ stats)
{
    __shared__ float x_s[2*81*64];      // XOR-swizzled [img][9x9 rows][64ch], 40.5 KiB
    __shared__ float bs[32], bq[32];

    const int tid  = threadIdx.x;
    const int wave = tid >> 6;
    const int lane = tid & 63;
    const int b0   = blockIdx.x << 1;

    for (int i = tid; i < 2*81*64; i += 256) x_s[i] = 0.f;
    if (tid < 32) { bs[tid] = 0.f; bq[tid] = 0.f; }
    __syncthreads();

    for (int img = 0; img < 2; ++img) {
        const float* zb = zq + (long long)(b0+img)*3136;
        for (int i = tid; i < 3136; i += 256) {
            int c = i / 49, hw = i - c*49;
            int ih = hw / 7, iw = hw - ih*7;
            int r = (ih+1)*9 + (iw+1);
            int slot = (c >> 2) ^ (r & 7);
            x_s[img*5184 + r*64 + (slot << 2) + (c & 3)] = zb[i];
        }
    }
    __syncthreads();

    const int oc0u = __builtin_amdgcn_readfirstlane(wave << 3);
    float bias[8];
    #pragma unroll
    for (int j = 0; j < 8; ++j) bias[j] = b1[oc0u + j];

    const bool act = lane < 49;
    const int  la  = act ? lane : 0;
    const int  a   = la / 7;
    const int  bb  = la - a*7;

    float ts[8], tq[8];
    #pragma unroll
    for (int j = 0; j < 8; ++j) { ts[j] = 0.f; tq[j] = 0.f; }

    for (int cls = 0; cls < 4; ++cls) {
        const int ph = cls >> 1, pw = cls & 1;
        const int oh = 2*a + ph, ow = 2*bb + pw;
        for (int img = 0; img < 2; ++img) {
            float acc[8];
            #pragma unroll
            for (int j = 0; j < 8; ++j) acc[j] = 0.f;
            #pragma unroll
            for (int dh = 0; dh < 2; ++dh) {
                #pragma unroll
                for (int dw = 0; dw < 2; ++dw) {
                    const int ih = a + ph - dh, iw = bb + pw - dw;
                    const int r  = (ih+1)*9 + (iw+1);
                    const int rx = r & 7;
                    const int rbase = img*5184 + r*64;
                    const int kh = (1-ph) + 2*dh, kw = (1-pw) + 2*dw;
                    const float* wb = w1t + (((kh<<2)+kw) << 11) + oc0u;   // uniform
                    #pragma unroll
                    for (int ic4 = 0; ic4 < 16; ++ic4) {
                        const float4 xv = *(const float4*)&x_s[rbase + ((ic4 ^ rx) << 2)];
                        const float* wr = wb + (ic4 << 7);                  // uniform
                        OC8(xv.x, wr); OC8(xv.y, wr+32); OC8(xv.z, wr+64); OC8(xv.w, wr+96);
                    }
                }
            }
            if (act) {
                float* cp = c1raw + (long long)(b0+img)*6272 + oh*14 + ow;
                #pragma unroll
                for (int j = 0; j < 8; ++j) {
                    float v = acc[j] + bias[j];
                    cp[(oc0u + j)*196] = v;
                    ts[j] += v; tq[j] = fmaf(v, v, tq[j]);
                }
            }
        }
    }

    #pragma unroll
    for (int j = 0; j < 8; ++j) {
        atomicAdd(&bs[oc0u + j], ts[j]);
        atomicAdd(&bq[oc0u + j], tq[j]);
    }
    __syncthreads();
    if (tid < 32) {
        atomicAdd(&stats[tid],      (double)bs[tid]);
        atomicAdd(&stats[32 + tid], (double)bq[tid]);
    }
}

// ---------------- K3/K5: fold BN stats into scale/shift ----------------
__global__ void k_bnfin(const double* __restrict__ stats, const float* __restrict__ g,
                        const float* __restrict__ be, float* __restrict__ bn,
                        int soff, int boff, int nch, double n)
{
    int t = threadIdx.x;
    if (t < nch) {
        double mean = stats[soff + t] / n;
        double var  = stats[soff + nch + t] / n - mean*mean;
        double rstd = 1.0 / sqrt(var + 1e-5);
        double sc   = (double)g[t] * rstd;
        bn[boff + t]       = (float)sc;
        bn[boff + nch + t] = (float)((double)be[t] - mean*sc);
    }
}

// ---------------- K4: BN1+ReLU on read, deconv2 (32->16, 14->28), BN2 stats ----------------
// 1 image per block; wave -> (oc half, px half); weights via s_load
__global__ __launch_bounds__(256) void k4_deconv2(
    const float* __restrict__ c1raw, const float* __restrict__ w2t,
    const float* __restrict__ b2, const float* __restrict__ bn,
    float* __restrict__ c2raw, double* __restrict__ stats)
{
    __shared__ float x_s[256*32];       // XOR-swizzled [16x16 rows][32ch], 32 KiB
    __shared__ float bs[16], bq[16];

    const int tid  = threadIdx.x;
    const int wave = tid >> 6;
    const int lane = tid & 63;
    const int b    = blockIdx.x;

    for (int i = tid; i < 256*32; i += 256) x_s[i] = 0.f;
    if (tid < 16) { bs[tid] = 0.f; bq[tid] = 0.f; }
    __syncthreads();

    const float* cb = c1raw + (long long)b*6272;
    for (int i = tid; i < 6272; i += 256) {
        int ic = i / 196, hw = i - ic*196;
        int ih = hw / 14, iw = hw - ih*14;
        float v = fmaxf(fmaf(cb[i], bn[ic], bn[32 + ic]), 0.f);
        int r = (ih+1)*16 + (iw+1);
        int slot = (ic >> 2) ^ (r & 7);
        x_s[r*32 + (slot << 2) + (ic & 3)] = v;
    }
    __syncthreads();

    const int oc0u   = __builtin_amdgcn_readfirstlane((wave & 1) << 3);
    const int pxhalf = wave >> 1;
    float bias[8];
    #pragma unroll
    for (int j = 0; j < 8; ++j) bias[j] = b2[oc0u + j];

    float ts[8], tq[8];
    #pragma unroll
    for (int j = 0; j < 8; ++j) { ts[j] = 0.f; tq[j] = 0.f; }

    float* c2b = c2raw + (long long)b*12544;

    for (int cls = 0; cls < 4; ++cls) {
        const int ph = cls >> 1, pw = cls & 1;
        for (int s = 0; s < 2; ++s) {
            const int qi  = s*64 + lane;
            const bool act = qi < 98;
            const int  q   = pxhalf*98 + (act ? qi : 0);
            const int  a   = q / 14;
            const int  bb  = q - a*14;
            const int  oh = 2*a + ph, ow = 2*bb + pw;
            float acc[8];
            #pragma unroll
            for (int j = 0; j < 8; ++j) acc[j] = 0.f;
            #pragma unroll
            for (int dh = 0; dh < 2; ++dh) {
                #pragma unroll
                for (int dw = 0; dw < 2; ++dw) {
                    const int ih = a + ph - dh, iw = bb + pw - dw;
                    const int r  = (ih+1)*16 + (iw+1);
                    const int rx = r & 7;
                    const int rbase = r*32;
                    const int kh = (1-ph) + 2*dh, kw = (1-pw) + 2*dw;
                    const float* wb = w2t + (((kh<<2)+kw) << 9) + oc0u;    // uniform
                    #pragma unroll
                    for (int ic4 = 0; ic4 < 8; ++ic4) {
                        const float4 xv = *(const float4*)&x_s[rbase + ((ic4 ^ rx) << 2)];
                        const float* wr = wb + (ic4 << 6);                  // uniform
                        OC8(xv.x, wr); OC8(xv.y, wr+16); OC8(xv.z, wr+32); OC8(xv.w, wr+48);
                    }
                }
            }
            if (act) {
                float* cp = c2b + oh*28 + ow;
                #pragma unroll
                for (int j = 0; j < 8; ++j) {
                    float v = acc[j] + bias[j];
                    cp[(oc0u + j)*784] = v;
                    ts[j] += v; tq[j] = fmaf(v, v, tq[j]);
                }
            }
        }
    }

    #pragma unroll
    for (int j = 0; j < 8; ++j) {
        atomicAdd(&bs[oc0u + j], ts[j]);
        atomicAdd(&bq[oc0u + j], tq[j]);
    }
    __syncthreads();
    if (tid < 16) {
        atomicAdd(&stats[64 + tid], (double)bs[tid]);
        atomicAdd(&stats[80 + tid], (double)bq[tid]);
    }
}

// ---------------- K6: BN2+ReLU on read, 3x3 conv 16->1, sigmoid ----------------
__global__ __launch_bounds__(256) void k6_conv(
    const float* __restrict__ c2raw, const float* __restrict__ cw,
    const float* __restrict__ cbias, const float* __restrict__ bn,
    float* __restrict__ out)
{
    __shared__ float x_s[30*30*20];     // padded [30][30][stride 20] 70.3 KiB (bank-spread)
    __shared__ float w_s[144];          // [khw=9][ic=16]

    const int tid = threadIdx.x;
    const int b = blockIdx.x;

    for (int i = tid; i < 30*30*20; i += 256) x_s[i] = 0.f;
    if (tid < 144) {
        int ic = tid / 9, khw = tid - ic*9;   // cw is [ic=16][kh][kw]
        w_s[khw*16 + ic] = cw[tid];
    }
    __syncthreads();

    const float* cr = c2raw + (long long)b*12544;
    for (int i = tid; i < 12544; i += 256) {
        int c = i / 784, hw = i - c*784;
        int ih = hw / 28, iw = hw - ih*28;
        float v = fmaxf(fmaf(cr[i], bn[64 + c], bn[80 + c]), 0.f);
        x_s[((ih+1)*30 + (iw+1))*20 + c] = v;
    }
    __syncthreads();

    const float bias = cbias[0];
    for (int pass = 0; pass < 4; ++pass) {
        int px = tid + (pass << 8);
        if (px >= 784) break;
        int oh = px / 28, ow = px - oh*28;
        float a0=0.f,a1=0.f,a2=0.f,a3=0.f;
        #pragma unroll
        for (int kh = 0; kh < 3; ++kh) {
            #pragma unroll
            for (int kw = 0; kw < 3; ++kw) {
                const float4* xv = (const float4*)&x_s[((oh+kh)*30 + (ow+kw))*20];
                const float4* wv = (const float4*)&w_s[((kh*3 + kw) << 4)];
                #pragma unroll
                for (int c4 = 0; c4 < 4; ++c4) {
                    float4 xx = xv[c4];
                    float4 ww = wv[c4];
                    a0 = fmaf(xx.x, ww.x, a0);
                    a1 = fmaf(xx.y, ww.y, a1);
                    a2 = fmaf(xx.z, ww.z, a2);
                    a3 = fmaf(xx.w, ww.w, a3);
                }
            }
        }
        float t = ((a0+a1) + (a2+a3)) + bias;
        out[(long long)b*784 + px] = 1.f / (1.f + expf(-t));
    }
}

// ---------------- launch ----------------
extern "C" void kernel_launch(void* const* d_in, const int* in_sizes, int n_in,
                              void* d_out, int out_size, void* d_ws, size_t ws_size,
                              hipStream_t stream) {
    const int*   x    = (const int*)d_in[0];
    const float* encW = (const float*)d_in[1];
    const float* emb  = (const float*)d_in[2];
    const float* w1   = (const float*)d_in[3];
    const float* b1   = (const float*)d_in[4];
    const float* g1   = (const float*)d_in[5];
    const float* be1  = (const float*)d_in[6];
    const float* w2   = (const float*)d_in[7];
    const float* b2   = (const float*)d_in[8];
    const float* g2   = (const float*)d_in[9];
    const float* be2  = (const float*)d_in[10];
    const float* cw   = (const float*)d_in[11];
    const float* cb   = (const float*)d_in[12];
    float* out = (float*)d_out;

    char* ws = (char*)d_ws;
    float*  c1raw = (float*)(ws + WS_C1);
    float*  c2raw = (float*)(ws + WS_C2);
    double* stats = (double*)(ws + WS_ST);
    float*  bn    = (float*)(ws + WS_BN);
    float*  w1t   = (float*)(ws + WS_W1T);
    float*  w2t   = (float*)(ws + WS_W2T);

    k_zero<<<1, 128, 0, stream>>>(stats);
    k_prep<<<128, 256, 0, stream>>>(w1, w2, w1t, w2t);
    k1_encode<<<784, 256, 0, stream>>>(x, encW, emb, out);
    k2_deconv1<<<2048, 256, 0, stream>>>(out + ZQ_OFF, w1t, b1, c1raw, stats);
    k_bnfin<<<1, 64, 0, stream>>>(stats, g1, be1, bn, 0, 0, 32, 4096.0*196.0);
    k4_deconv2<<<4096, 256, 0, stream>>>(c1raw, w2t, b2, bn, c2raw, stats);
    k_bnfin<<<1, 64, 0, stream>>>(stats, g2, be2, bn, 64, 64, 16, 4096.0*784.0);
    k6_conv<<<4096, 256, 0, stream>>>(c2raw, cw, cb, bn, out);
}